// Round 1
// baseline (24.465 us; speedup 1.0000x reference)
//
#include <hip/hip_runtime.h>
#include <hip/hip_bf16.h>

// WithLSHSort reduces to the identity:
//   idx = argsort(angles) is a permutation along S per (b, h);
//   inv = argsort(idx) is its exact inverse permutation;
//   gather(gather(x, idx), inv) == x  (exactly, independent of the angles).
// Therefore out = x. The projection / arctan / sorts are dead computation.
// Optimal implementation: a D2D copy of x (64 MiB fp32) into d_out.

extern "C" void kernel_launch(void* const* d_in, const int* in_sizes, int n_in,
                              void* d_out, int out_size, void* d_ws, size_t ws_size,
                              hipStream_t stream) {
    const float* x = (const float*)d_in[0];
    float* out = (float*)d_out;
    size_t bytes = (size_t)out_size * sizeof(float);
    hipMemcpyAsync(out, x, bytes, hipMemcpyDeviceToDevice, stream);
}